// Round 4
// baseline (83.501 us; speedup 1.0000x reference)
//
#include <hip/hip_runtime.h>
#include <hip/hip_bf16.h>

// Problem constants (fixed by the reference setup)
#define B_  16
#define C_  64
#define H_  64
#define W_  64
#define O_  64
#define EPS 1e-6f
#define SLOPE 0.01f

typedef __bf16  bf16x8 __attribute__((ext_vector_type(8)));
typedef float   f32x4  __attribute__((ext_vector_type(4)));

// ---- static LDS layout (bytes) ----
// x tile: [r(4)][w(64)][p(2)][c2(32)] bf16, row stride 144 B (16B aligned)
#define XT_OFF   0
#define XT_SZ    36864          // 4 * 64 * 144
#define PMIN_OFF 36864          // float[p(2)][r(4)][w(64)]
#define PMAX_OFF 38912
#define SINV_OFF 40960          // float[hh(2)][p(2)][w(64)]  1/(s+eps)
#define SEPS_OFF 43008          // float[hh(2)][p(2)][w(64)]  (s+eps)
#define SMEM_SZ  45056

__device__ __forceinline__ unsigned short f2bf(float f) {
  unsigned u = __float_as_uint(f);         // fp32 -> bf16 RNE
  u += 0x7fffu + ((u >> 16) & 1u);
  return (unsigned short)(u >> 16);
}

__device__ __forceinline__ int clampi(int v, int lo, int hi) {
  return v < lo ? lo : (v > hi ? hi : v);
}

// Transform W[o][c][j][i] (fp32) -> bf16 Wt[((tap*2+p)*64 + o)*32 + c2],
// tap = i*3+j (einsum 'bcijhw,ocji': tap (i,j) uses W[o][c][j][i]).
// Per-wave A-frag load is one coalesced 1KB global_load_dwordx4.
__global__ void wtransform_kernel(const float* __restrict__ Wsrc,
                                  unsigned short* __restrict__ Wt) {
  int idx = blockIdx.x * 256 + threadIdx.x;      // 64*64*9 = 36864 exact
  if (idx >= O_ * C_ * 9) return;
  int i = idx % 3;
  int j = (idx / 3) % 3;
  int c = (idx / 9) % C_;
  int o = idx / (9 * C_);
  int tap = i * 3 + j;
  Wt[((tap * 2 + (c & 1)) * 64 + o) * 32 + (c >> 1)] = f2bf(Wsrc[idx]);
}

// One block = one (b, h0) pair of output rows. 4 waves; wave wv owns o-slice
// o0 = wv*16, computes 16o x (2 rows x 64 w). Weights in VGPRs, ONE parity at
// a time (p-loop rolled) to keep peak VGPR ~130 — no spills under (256,3).
__launch_bounds__(256, 3)
__global__ void conv_main_kernel(const float* __restrict__ x,
                                 const unsigned short* __restrict__ Wt,
                                 const float* __restrict__ bias,
                                 float* __restrict__ out) {
  __shared__ char smem[SMEM_SZ];
  const int tid  = threadIdx.x;
  const int lane = tid & 63;
  const int wv   = tid >> 6;
  const int b    = blockIdx.x >> 5;
  const int h0   = (blockIdx.x & 31) << 1;

  // ---- stage x rows h0-1..h0+2 (replicate-clamped) into [r][w][p][c2] bf16,
  //      folding per-(r,p,w) fp32 min/max into the same pass.
  {
    const int w = tid & 63;
    const int r = tid >> 6;
    const int hr = clampi(h0 - 1 + r, 0, H_ - 1);
    const float* xb = x + ((size_t)b * C_ * H_ * W_) + hr * W_ + w;
    float mn[2] = {3.4e38f, 3.4e38f}, mx[2] = {-3.4e38f, -3.4e38f};
    #pragma unroll
    for (int pm = 0; pm < 8; ++pm) {
      const int p = pm >> 2, m = pm & 3;
      unsigned d[4];
      #pragma unroll
      for (int e = 0; e < 4; ++e) {
        const int c2a = m * 8 + 2 * e;
        const float f0 = xb[(2 * c2a + p) * (H_ * W_)];
        const float f1 = xb[(2 * (c2a + 1) + p) * (H_ * W_)];
        mn[p] = fminf(mn[p], fminf(f0, f1));
        mx[p] = fmaxf(mx[p], fmaxf(f0, f1));
        d[e] = (unsigned)f2bf(f0) | ((unsigned)f2bf(f1) << 16);
      }
      *(uint4*)(smem + XT_OFF + (r * 64 + w) * 144 + p * 64 + m * 16) =
          make_uint4(d[0], d[1], d[2], d[3]);
    }
    ((float*)(smem + PMIN_OFF))[(0 * 4 + r) * 64 + w] = mn[0];
    ((float*)(smem + PMIN_OFF))[(1 * 4 + r) * 64 + w] = mn[1];
    ((float*)(smem + PMAX_OFF))[(0 * 4 + r) * 64 + w] = mx[0];
    ((float*)(smem + PMAX_OFF))[(1 * 4 + r) * 64 + w] = mx[1];
  }
  __syncthreads();

  // ---- s-pass: 3x3 window reduce -> (s+eps), 1/(s+eps) per (row hh, p, w)
  {
    const int hh = tid >> 7, p = (tid >> 6) & 1, w = tid & 63;
    const float* pmin = (const float*)(smem + PMIN_OFF);
    const float* pmax = (const float*)(smem + PMAX_OFF);
    float mn = 3.4e38f, mx = -3.4e38f;
    #pragma unroll
    for (int r = 0; r < 3; ++r) {
      #pragma unroll
      for (int dw = -1; dw <= 1; ++dw) {
        const int wc = clampi(w + dw, 0, W_ - 1);
        mn = fminf(mn, pmin[(p * 4 + (hh + r)) * 64 + wc]);
        mx = fmaxf(mx, pmax[(p * 4 + (hh + r)) * 64 + wc]);
      }
    }
    const float sv = (mx - mn) + EPS;
    ((float*)(smem + SEPS_OFF))[(hh * 2 + p) * 64 + w] = sv;
    ((float*)(smem + SINV_OFF))[(hh * 2 + p) * 64 + w] = 1.0f / sv;
  }
  __syncthreads();

  // ---- MFMA main loop: one parity at a time; fold acc*sinv into oacc after
  //      each parity so only one parity's accumulators are ever live.
  const int o0  = wv * 16;
  const int l15 = lane & 15;
  const int q   = lane >> 4;
  const float* sinv = (const float*)(smem + SINV_OFF);

  const f32x4 zero = {0.0f, 0.0f, 0.0f, 0.0f};
  f32x4 oacc[2][4];                   // [hh][nt], normalized+summed over p
  #pragma unroll
  for (int hh = 0; hh < 2; ++hh)
    #pragma unroll
    for (int nt = 0; nt < 4; ++nt) oacc[hh][nt] = zero;

  #pragma unroll 1
  for (int p = 0; p < 2; ++p) {
    bf16x8 af[9];                     // A[m=o][k=c2], m=lane&15, k=q*8+j
    #pragma unroll
    for (int t9 = 0; t9 < 9; ++t9)
      af[t9] = *(const bf16x8*)(Wt + ((t9 * 2 + p) * 64 + o0 + l15) * 32 + q * 8);

    f32x4 acc[2][4];                  // [hh][nt] for this parity
    #pragma unroll
    for (int hh = 0; hh < 2; ++hh)
      #pragma unroll
      for (int nt = 0; nt < 4; ++nt) acc[hh][nt] = zero;

    #pragma unroll
    for (int xr = 0; xr < 4; ++xr) {
      #pragma unroll
      for (int nt = 0; nt < 4; ++nt) {
        bf16x8 bfr[3];                // B[k=c2][n=w], n=lane&15, k=q*8+j
        #pragma unroll
        for (int j = 0; j < 3; ++j) {
          const int wc = clampi(nt * 16 + l15 + j - 1, 0, W_ - 1);
          bfr[j] = *(const bf16x8*)(smem + XT_OFF + (xr * 64 + wc) * 144 + p * 64 + q * 16);
        }
        #pragma unroll
        for (int hh = 0; hh < 2; ++hh) {
          const int i = xr - hh;      // kernel row offset; valid 0..2
          if (i >= 0 && i < 3) {
            #pragma unroll
            for (int j = 0; j < 3; ++j)
              acc[hh][nt] = __builtin_amdgcn_mfma_f32_16x16x32_bf16(
                  af[i * 3 + j], bfr[j], acc[hh][nt], 0, 0, 0);
          }
        }
      }
    }

    // fold this parity: oacc += acc * 1/(s_p + eps)   (sv uniform over regs)
    #pragma unroll
    for (int hh = 0; hh < 2; ++hh) {
      #pragma unroll
      for (int nt = 0; nt < 4; ++nt) {
        const float sv = sinv[(hh * 2 + p) * 64 + nt * 16 + l15];
        #pragma unroll
        for (int reg = 0; reg < 4; ++reg)
          oacc[hh][nt][reg] += acc[hh][nt][reg] * sv;
      }
    }
  }

  // ---- epilogue: bias, leaky-relu, re-scale by (s_{o%2}+eps), store fp32 ----
  // D layout: col(w) = lane&15, row(o-within-16) = (lane>>4)*4 + reg
  const float* seps = (const float*)(smem + SEPS_OFF);
  float bv[4];
  #pragma unroll
  for (int reg = 0; reg < 4; ++reg) bv[reg] = bias[o0 + q * 4 + reg];

  #pragma unroll
  for (int hh = 0; hh < 2; ++hh) {
    #pragma unroll
    for (int nt = 0; nt < 4; ++nt) {
      const int wpx = nt * 16 + l15;
      const float se0 = seps[(hh * 2 + 0) * 64 + wpx];
      const float se1 = seps[(hh * 2 + 1) * 64 + wpx];
      #pragma unroll
      for (int reg = 0; reg < 4; ++reg) {
        const int o = o0 + q * 4 + reg;
        float v = oacc[hh][nt][reg] + bv[reg];
        v = v >= 0.0f ? v : SLOPE * v;
        v *= (reg & 1) ? se1 : se0;          // o&1 == reg&1 (q*4 even)
        out[((b * O_ + o) * H_ + (h0 + hh)) * W_ + wpx] = v;
      }
    }
  }
}

extern "C" void kernel_launch(void* const* d_in, const int* in_sizes, int n_in,
                              void* d_out, int out_size, void* d_ws, size_t ws_size,
                              hipStream_t stream) {
  const float* x    = (const float*)d_in[0];
  const float* Wsrc = (const float*)d_in[1];
  const float* bias = (const float*)d_in[2];
  float* out = (float*)d_out;
  unsigned short* Wt = (unsigned short*)d_ws;   // 73,728 B bf16 weight scratch

  wtransform_kernel<<<144, 256, 0, stream>>>(Wsrc, Wt);
  conv_main_kernel<<<512, 256, 0, stream>>>(x, Wt, bias, out);
}

// Round 5
// 83.457 us; speedup vs baseline: 1.0005x; 1.0005x over previous
//
#include <hip/hip_runtime.h>
#include <hip/hip_bf16.h>

// Problem constants (fixed by the reference setup)
#define B_  16
#define C_  64
#define H_  64
#define W_  64
#define O_  64
#define EPS 1e-6f
#define SLOPE 0.01f

typedef __bf16  bf16x8 __attribute__((ext_vector_type(8)));
typedef float   f32x4  __attribute__((ext_vector_type(4)));

// ---- static LDS layout (bytes) ----
#define XT_OFF   0            // bf16 [r(4)][w(64)][p(2)][c2(32)], row stride 144 B
#define XT_SZ    36864
#define RAW_OFF  36864        // fp32 [rloc(2)][c(64)][w(64)] raw DMA target, 32 KB
#define RAW_SZ   32768
#define PMIN_OFF 69632        // float [p(2)][r(4)][cs(2)][w(64)] = 4096 B
#define PMAX_OFF 73728        // 4096 B
#define SINV_OFF 77824        // float [hh(2)][p(2)][w(64)] = 1024 B
#define SEPS_OFF 78848        // 1024 B
#define SMEM_SZ  79872        // 78 KB -> 2 blocks/CU (2*78 <= 160 KB)

__device__ __forceinline__ unsigned short f2bf(float f) {
  unsigned u = __float_as_uint(f);         // fp32 -> bf16 RNE
  u += 0x7fffu + ((u >> 16) & 1u);
  return (unsigned short)(u >> 16);
}

__device__ __forceinline__ int clampi(int v, int lo, int hi) {
  return v < lo ? lo : (v > hi ? hi : v);
}

// Transform W[o][c][j][i] (fp32) -> bf16 Wt[((tap*2+p)*64 + o)*32 + c2],
// tap = i*3+j (einsum 'bcijhw,ocji': tap (i,j) uses W[o][c][j][i]).
__global__ void wtransform_kernel(const float* __restrict__ Wsrc,
                                  unsigned short* __restrict__ Wt) {
  int idx = blockIdx.x * 256 + threadIdx.x;      // 64*64*9 = 36864 exact
  if (idx >= O_ * C_ * 9) return;
  int i = idx % 3;
  int j = (idx / 3) % 3;
  int c = (idx / 9) % C_;
  int o = idx / (9 * C_);
  int tap = i * 3 + j;
  Wt[((tap * 2 + (c & 1)) * 64 + o) * 32 + (c >> 1)] = f2bf(Wsrc[idx]);
}

// One block = one (b, h0) pair of output rows. 4 waves; wave wv owns o-slice
// o0 = wv*16, computes 16o x (2 rows x 64 w). x staged via async
// global_load_lds (raw fp32) then transformed LDS->LDS to the bf16 MFMA tile.
__launch_bounds__(256, 2)
__global__ void conv_main_kernel(const float* __restrict__ x,
                                 const unsigned short* __restrict__ Wt,
                                 const float* __restrict__ bias,
                                 float* __restrict__ out) {
  __shared__ char smem[SMEM_SZ];
  const int tid  = threadIdx.x;
  const int lane = tid & 63;
  const int wv   = tid >> 6;
  const int b    = blockIdx.x >> 5;
  const int h0   = (blockIdx.x & 31) << 1;
  const int l15  = lane & 15;
  const int q    = lane >> 4;
  const int o0   = wv * 16;

  // ---- preload all weight fragments into VGPRs (overlaps the DMA below) ----
  bf16x8 af[2][9];                     // [p][tap]; A[m=o][k=c2], m=lane&15
  #pragma unroll
  for (int p = 0; p < 2; ++p)
    #pragma unroll
    for (int t9 = 0; t9 < 9; ++t9)
      af[p][t9] = *(const bf16x8*)(Wt + ((t9 * 2 + p) * 64 + o0 + l15) * 32 + q * 8);

  // ---- stage + transform x rows in two row-pair phases ----
  const int w  = tid & 63;
  const int rc = tid >> 6;             // 0..3
  const int rloc_t = rc & 1;           // row within pair (transform role)
  const int cs = rc >> 1;              // channel half (transform role)

  #pragma unroll 1
  for (int rp = 0; rp < 2; ++rp) {
    // async DMA: 128 rows of 256 B (2 rows x 64 ch), 32 wave-instrs per wave
    #pragma unroll
    for (int it = 0; it < 32; ++it) {
      const int idx  = wv * 32 + it;
      const int rl   = idx >> 6;       // 0..1
      const int c    = idx & 63;
      const int hr   = clampi(h0 - 1 + rp * 2 + rl, 0, H_ - 1);
      const float* g = x + (((b * C_ + c) * H_ + hr) * W_) + lane;
      __builtin_amdgcn_global_load_lds(
          (const __attribute__((address_space(1))) unsigned*)g,
          (__attribute__((address_space(3))) unsigned*)(smem + RAW_OFF + (rl * 64 + c) * 256),
          4, 0, 0);
    }
    asm volatile("s_waitcnt vmcnt(0)" ::: "memory");
    __syncthreads();

    // transform: thread (rloc_t, cs, w) reads 32 channels (fp32, conflict-free
    // b32, stride 256 B), computes per-parity min/max, packs bf16 -> XT.
    {
      const int r = rp * 2 + rloc_t;   // global tile row 0..3
      const float* rawp = (const float*)(smem + RAW_OFF) + rloc_t * 4096 + w;
      float mn[2] = {3.4e38f, 3.4e38f}, mx[2] = {-3.4e38f, -3.4e38f};
      unsigned pk[2][8];
      #pragma unroll
      for (int k = 0; k < 32; ++k) {
        const int c = cs * 32 + k;
        const float f = rawp[c * 64];
        const int p = k & 1;
        const int u = k >> 1;          // 0..15 -> c2 = cs*16+u
        mn[p] = fminf(mn[p], f);
        mx[p] = fmaxf(mx[p], f);
        const unsigned h = f2bf(f);
        if (u & 1) pk[p][u >> 1] |= (h << 16);
        else       pk[p][u >> 1]  = h;
      }
      char* xtw = smem + XT_OFF + (r * 64 + w) * 144 + cs * 32;
      *(uint4*)(xtw)      = make_uint4(pk[0][0], pk[0][1], pk[0][2], pk[0][3]);
      *(uint4*)(xtw + 16) = make_uint4(pk[0][4], pk[0][5], pk[0][6], pk[0][7]);
      *(uint4*)(xtw + 64) = make_uint4(pk[1][0], pk[1][1], pk[1][2], pk[1][3]);
      *(uint4*)(xtw + 80) = make_uint4(pk[1][4], pk[1][5], pk[1][6], pk[1][7]);
      ((float*)(smem + PMIN_OFF))[((0 * 4 + r) * 2 + cs) * 64 + w] = mn[0];
      ((float*)(smem + PMIN_OFF))[((1 * 4 + r) * 2 + cs) * 64 + w] = mn[1];
      ((float*)(smem + PMAX_OFF))[((0 * 4 + r) * 2 + cs) * 64 + w] = mx[0];
      ((float*)(smem + PMAX_OFF))[((1 * 4 + r) * 2 + cs) * 64 + w] = mx[1];
    }
    __syncthreads();   // raw fully consumed before next DMA overwrites it
  }

  // ---- s-pass: 3x3 window + cs reduce -> (s+eps), 1/(s+eps) per (hh, p, w)
  {
    const int hh = tid >> 7, p = (tid >> 6) & 1, ww = tid & 63;
    const float* pmin = (const float*)(smem + PMIN_OFF);
    const float* pmax = (const float*)(smem + PMAX_OFF);
    float mn = 3.4e38f, mx = -3.4e38f;
    #pragma unroll
    for (int r = 0; r < 3; ++r) {
      #pragma unroll
      for (int dw = -1; dw <= 1; ++dw) {
        const int wc = clampi(ww + dw, 0, W_ - 1);
        #pragma unroll
        for (int c2s = 0; c2s < 2; ++c2s) {
          mn = fminf(mn, pmin[((p * 4 + (hh + r)) * 2 + c2s) * 64 + wc]);
          mx = fmaxf(mx, pmax[((p * 4 + (hh + r)) * 2 + c2s) * 64 + wc]);
        }
      }
    }
    const float sv = (mx - mn) + EPS;
    ((float*)(smem + SEPS_OFF))[(hh * 2 + p) * 64 + ww] = sv;
    ((float*)(smem + SINV_OFF))[(hh * 2 + p) * 64 + ww] = 1.0f / sv;
  }
  __syncthreads();

  // ---- MFMA main loop: fold acc*sinv into oacc after each parity ----
  const float* sinv = (const float*)(smem + SINV_OFF);
  const f32x4 zero = {0.0f, 0.0f, 0.0f, 0.0f};
  f32x4 oacc[2][4];                   // [hh][nt]
  #pragma unroll
  for (int hh = 0; hh < 2; ++hh)
    #pragma unroll
    for (int nt = 0; nt < 4; ++nt) oacc[hh][nt] = zero;

  #pragma unroll
  for (int p = 0; p < 2; ++p) {
    f32x4 acc[2][4];
    #pragma unroll
    for (int hh = 0; hh < 2; ++hh)
      #pragma unroll
      for (int nt = 0; nt < 4; ++nt) acc[hh][nt] = zero;

    #pragma unroll
    for (int xr = 0; xr < 4; ++xr) {
      #pragma unroll
      for (int nt = 0; nt < 4; ++nt) {
        bf16x8 bfr[3];                // B[k=c2][n=w], n=lane&15, k=q*8+u
        #pragma unroll
        for (int j = 0; j < 3; ++j) {
          const int wc = clampi(nt * 16 + l15 + j - 1, 0, W_ - 1);
          bfr[j] = *(const bf16x8*)(smem + XT_OFF + (xr * 64 + wc) * 144 + p * 64 + q * 16);
        }
        #pragma unroll
        for (int hh = 0; hh < 2; ++hh) {
          const int i = xr - hh;      // kernel row offset; valid 0..2
          if (i >= 0 && i < 3) {
            #pragma unroll
            for (int j = 0; j < 3; ++j)
              acc[hh][nt] = __builtin_amdgcn_mfma_f32_16x16x32_bf16(
                  af[p][i * 3 + j], bfr[j], acc[hh][nt], 0, 0, 0);
          }
        }
      }
    }

    #pragma unroll
    for (int hh = 0; hh < 2; ++hh)
      #pragma unroll
      for (int nt = 0; nt < 4; ++nt) {
        const float sv = sinv[(hh * 2 + p) * 64 + nt * 16 + l15];
        #pragma unroll
        for (int reg = 0; reg < 4; ++reg)
          oacc[hh][nt][reg] += acc[hh][nt][reg] * sv;
      }
  }

  // ---- epilogue: bias, leaky-relu, re-scale by (s_{o%2}+eps), store fp32 ----
  // D layout: col(w) = lane&15, row(o-within-16) = (lane>>4)*4 + reg
  const float* seps = (const float*)(smem + SEPS_OFF);
  float bv[4];
  #pragma unroll
  for (int reg = 0; reg < 4; ++reg) bv[reg] = bias[o0 + q * 4 + reg];

  #pragma unroll
  for (int hh = 0; hh < 2; ++hh) {
    #pragma unroll
    for (int nt = 0; nt < 4; ++nt) {
      const int wpx = nt * 16 + l15;
      const float se0 = seps[(hh * 2 + 0) * 64 + wpx];
      const float se1 = seps[(hh * 2 + 1) * 64 + wpx];
      #pragma unroll
      for (int reg = 0; reg < 4; ++reg) {
        const int o = o0 + q * 4 + reg;
        float v = oacc[hh][nt][reg] + bv[reg];
        v = v >= 0.0f ? v : SLOPE * v;
        v *= (reg & 1) ? se1 : se0;          // o&1 == reg&1 (q*4 even)
        out[((b * O_ + o) * H_ + (h0 + hh)) * W_ + wpx] = v;
      }
    }
  }
}

extern "C" void kernel_launch(void* const* d_in, const int* in_sizes, int n_in,
                              void* d_out, int out_size, void* d_ws, size_t ws_size,
                              hipStream_t stream) {
  const float* x    = (const float*)d_in[0];
  const float* Wsrc = (const float*)d_in[1];
  const float* bias = (const float*)d_in[2];
  float* out = (float*)d_out;
  unsigned short* Wt = (unsigned short*)d_ws;   // 73,728 B bf16 weight scratch

  wtransform_kernel<<<144, 256, 0, stream>>>(Wsrc, Wt);
  conv_main_kernel<<<512, 256, 0, stream>>>(x, Wt, bias, out);
}